// Round 7
// baseline (76.615 us; speedup 1.0000x reference)
//
#include <hip/hip_runtime.h>
#include <math.h>

#define HH 256
#define WW 256
#define KE 4096
#define NSLICE 16
#define NSPLIT 8                      // query splits per (slice,dir)
#define QPB (KE / NSPLIT)             // 512 queries per block
#define NBLK (NSLICE * 2 * NSPLIT)    // 256 blocks in k3
#define GCAP 1024                     // column-EDT cap/sentinel; 1024^2 > max real d2

typedef unsigned long long u64;
typedef unsigned short u16;

// ---------------------------------------------------------------------------
// K1: binarize + bit-pack. One block per image row (2 x 16 x 256 = 8192).
// Lane thresholds one pixel; ballot packs 64 cols -> u64.
// bm layout: [tensor][slice][row][word4]. Also zeroes k3's completion counter.
// ---------------------------------------------------------------------------
__global__ void __launch_bounds__(256) k1_binpack(
        const float* __restrict__ gth, const float* __restrict__ pred,
        u64* __restrict__ bm, int* __restrict__ counter) {
    int b = blockIdx.x;                 // tensor*4096 + slice*256 + row
    if (b == 0 && threadIdx.x == 0) *counter = 0;
    int tensor = b >> 12;
    int sr = b & 4095;
    const float* img = tensor ? pred : gth;
    float v = img[sr * WW + threadIdx.x];
    u64 bal = __ballot(v > 0.5f);
    if ((threadIdx.x & 63) == 0) bm[(size_t)b * 4 + (threadIdx.x >> 6)] = bal;
}

// ---------------------------------------------------------------------------
// K2: bitwise edge detect + ordered compaction + truncated edge bitmap.
// 32 blocks (tensor,slice), thread = row.
//   vert  = rowAbove & row & rowBelow      (OOB row = all-ones)
//   erode = vert & shl1 & shr1             (OOB col carry-in = 1)
//   edge  = row & ~erode
// Wave-shfl scan (1 barrier) -> ordered point writes (row-major ==
// jnp.nonzero). ebm keeps only bits of row-major rank < KE (the reference
// only ever sees the first KE points as targets). cnt = FULL count (divisor).
// ---------------------------------------------------------------------------
__global__ void __launch_bounds__(256) k2_edge_compact(
        const u64* __restrict__ bm,
        float2* __restrict__ gpts, float2* __restrict__ ppts,
        u64* __restrict__ ebm,
        int* __restrict__ gcnt, int* __restrict__ pcnt) {
    int b = blockIdx.x;                 // 0..31  (tensor*16 + slice)
    int tensor = b >> 4;
    int slice = b & 15;
    const u64* rm = bm + (size_t)(tensor * 4096 + slice * 256) * 4;
    float2* pts = (tensor ? ppts : gpts) + slice * KE;
    int* cnt = (tensor ? pcnt : gcnt) + slice;
    u64* eb = ebm + (size_t)b * 1024;   // 256 rows x 4 words

    int row = threadIdx.x;
    u64 vc[4], va[4], vb[4];
#pragma unroll
    for (int w = 0; w < 4; ++w) {
        vc[w] = rm[row * 4 + w];
        va[w] = (row > 0) ? rm[(row - 1) * 4 + w] : ~0ull;
        vb[w] = (row < HH - 1) ? rm[(row + 1) * 4 + w] : ~0ull;
    }
    u64 vert[4];
#pragma unroll
    for (int w = 0; w < 4; ++w) vert[w] = va[w] & vc[w] & vb[w];
    u64 e[4];
#pragma unroll
    for (int w = 0; w < 4; ++w) {
        u64 left  = (vert[w] << 1) | ((w > 0) ? (vert[w - 1] >> 63) : 1ull);
        u64 right = (vert[w] >> 1) | (((w < 3) ? (vert[w + 1] & 1ull) : 1ull) << 63);
        e[w] = vc[w] & ~(vert[w] & left & right);
    }
    int mycnt = __popcll(e[0]) + __popcll(e[1]) + __popcll(e[2]) + __popcll(e[3]);

    // Wave-level inclusive scan + cross-wave combine (1 barrier).
    int lane = row & 63, wv = row >> 6;
    int incl = mycnt;
    for (int d = 1; d < 64; d <<= 1) {
        int n = __shfl_up(incl, d, 64);
        if (lane >= d) incl += n;
    }
    __shared__ int wsum[4];
    if (lane == 63) wsum[wv] = incl;
    __syncthreads();
    int wpre = 0;
    for (int k = 0; k < 4; ++k) wpre += (k < wv) ? wsum[k] : 0;
    int off = wpre + incl - mycnt;      // exclusive prefix (row-major rank)

    // Truncated edge bitmap: keep only bits with rank < KE.
    int rem = KE - off;
    u64 t[4];
    if (rem >= mycnt) {
#pragma unroll
        for (int w = 0; w < 4; ++w) t[w] = e[w];
    } else if (rem <= 0) {
#pragma unroll
        for (int w = 0; w < 4; ++w) t[w] = 0ull;
    } else {
        int k = rem;
#pragma unroll
        for (int w = 0; w < 4; ++w) {
            int pc = __popcll(e[w]);
            if (k >= pc) { t[w] = e[w]; k -= pc; }
            else {
                u64 bits = e[w], keep = 0ull;
                for (int i = 0; i < k; ++i) {
                    u64 low = bits & (~bits + 1ull);
                    keep |= low;
                    bits ^= low;
                }
                t[w] = keep;
                k = 0;
            }
        }
    }
#pragma unroll
    for (int w = 0; w < 4; ++w) eb[row * 4 + w] = t[w];

    // Ordered point-list writes (queries; first KE in row-major order).
    int o = off;
#pragma unroll
    for (int w = 0; w < 4; ++w) {
        u64 bits = e[w];
        while (bits) {
            int l = __ffsll((long long)bits) - 1;
            bits &= bits - 1;
            if (o < KE) pts[o] = make_float2((float)row, (float)(w * 64 + l));
            ++o;
        }
    }
    if (row == HH - 1) *cnt = wpre + incl;
}

// ---------------------------------------------------------------------------
// G storage swizzle: u16 index of (r,c) with 16B-chunk XOR so that query-phase
// reads (different r per lane, same chunk j) spread across 8 bank groups.
// ---------------------------------------------------------------------------
__device__ __forceinline__ int gidx(int r, int c) {
    int cj = (c >> 3) ^ (r & 7);
    return r * WW + cj * 8 + (c & 7);
}

// ---------------------------------------------------------------------------
// K3: per-(slice,dir,split) fused EDT + NN-scan + (last block) finalize.
// 256 blocks x 1024 threads, 144 KB dynamic LDS.
//  Phase A: load target truncated edge bitmap (8 KB) -> LDS.
//  Phase B: vertical EDT entirely in LDS. Thread (c, rb) owns a 64-row
//    window of column c: gather window word (broadcast reads), publish
//    window lo/hi, O(1) boundary combine, down+up scans -> G[r][c] u16.
//  Phase C: 512 queries (split of the row-major pts list): scan the 256
//    G values of row r: d2 = min_c' ((c-c')^2 + G^2) -- exact ints ->
//    sqrt matches reference bitwise. Wave reduce -> block partial.
//  Phase D: release-store partial, count blocks; last block folds
//    partials -> per-slice ahd -> loss -> nanmean -> out.
// ---------------------------------------------------------------------------
__global__ void __launch_bounds__(1024) k3_sd_nn(
        const float2* __restrict__ gpts, const float2* __restrict__ ppts,
        const int* __restrict__ gcnt, const int* __restrict__ pcnt,
        const u64* __restrict__ ebm,
        float* __restrict__ partial, int* __restrict__ counter,
        float* __restrict__ out) {
    extern __shared__ char smem[];
    u64* ebl  = (u64*)smem;                 // [0, 8192)
    int* slo  = (int*)(smem + 8192);        // [8192, 12288)   (dead after EDT)
    int* shi  = (int*)(smem + 12288);       // [12288, 16384)  (dead after EDT)
    u16* G    = (u16*)(smem + 16384);       // [16384, 147456)
    float* red = (float*)(smem + 8192);     // reuse lo/hi region after EDT
    __shared__ int s_last;

    int bid = blockIdx.x;
    int split = bid & (NSPLIT - 1);
    int sd = bid >> 3;                      // slice*2 + dir
    int dir = sd & 1;
    int slice = sd >> 1;
    int tid = threadIdx.x;

    // ---- Phase A: target bitmap -> LDS ----
    int tt = dir ? 0 : 1;                   // dir0: g->p targets pred(1); dir1 -> gth(0)
    const u64* eb = ebm + (size_t)(tt * 16 + slice) * 1024;
    ebl[tid] = eb[tid];
    __syncthreads();

    // ---- Phase B: vertical EDT in LDS ----
    int c = tid & 255, rb = tid >> 8, base = rb << 6;
    int cw = c >> 6, cb = c & 63;
    u64 w = 0;
#pragma unroll 8
    for (int i = 0; i < 64; ++i)
        w |= ((ebl[(base + i) * 4 + cw] >> cb) & 1ull) << i;
    slo[c * 4 + rb] = w ? base + (__ffsll((long long)w) - 1) : 100000;
    shi[c * 4 + rb] = w ? base + (63 - __clzll((long long)w)) : -100000;
    __syncthreads();
    int hiA = -100000, loB = 100000;
#pragma unroll
    for (int k = 0; k < 4; ++k) {
        int lok = slo[c * 4 + k], hik = shi[c * 4 + k];
        if (k < rb) hiA = max(hiA, hik);
        if (k > rb) loB = min(loB, lok);
    }
    int g = min(base - 1 - hiA, GCAP);      // g at row base-1
    for (int i = 0; i < 64; ++i) {
        int bit = (int)((w >> i) & 1ull);
        g = bit ? 0 : min(g + 1, GCAP);
        G[gidx(base + i, c)] = (u16)g;
    }
    int gu = min(loB - (base + 64), GCAP);  // g' at row base+64
    for (int i = 63; i >= 0; --i) {
        int bit = (int)((w >> i) & 1ull);
        gu = bit ? 0 : min(gu + 1, GCAP);
        int ix = gidx(base + i, c);
        G[ix] = (u16)min((int)G[ix], gu);
    }
    __syncthreads();

    // ---- Phase C: query scan ----
    int qfull = dir ? pcnt[slice] : gcnt[slice];
    int qc = min(qfull, KE);
    float val = 0.0f;
    int qi = split * QPB + tid;
    if (tid < QPB && qi < qc) {
        const float2* q = (dir ? ppts : gpts) + slice * KE;
        float2 qp = q[qi];
        int r = (int)qp.x, cc = (int)qp.y;
        const uint4* grow = (const uint4*)(G + r * WW);
        int rsw = r & 7;
        int m = 0x7fffffff;
#pragma unroll
        for (int j = 0; j < 32; ++j) {
            uint4 v = grow[j ^ rsw];        // chunk j (cols 8j..8j+7), de-swizzled
            int bs = j * 8;
#define STEP(word, k0)                                                      \
            {                                                               \
                int g0 = (int)((word) & 0xffffu);                           \
                int g1 = (int)((word) >> 16);                               \
                int d0 = cc - (bs + k0);                                    \
                int d1 = cc - (bs + k0 + 1);                                \
                m = min(m, d0 * d0 + g0 * g0);                              \
                m = min(m, d1 * d1 + g1 * g1);                              \
            }
            STEP(v.x, 0) STEP(v.y, 2) STEP(v.z, 4) STEP(v.w, 6)
#undef STEP
        }
        val = sqrtf((float)m);
    }
    for (int s = 32; s > 0; s >>= 1) val += __shfl_xor(val, s, 64);
    if ((tid & 63) == 0) red[tid >> 6] = val;
    __syncthreads();

    // ---- Phase D: publish partial; last block finalizes ----
    if (tid == 0) {
        float qsum = 0.0f;
        for (int k = 0; k < 16; ++k) qsum += red[k];
        __hip_atomic_store(&partial[bid], qsum, __ATOMIC_RELEASE,
                           __HIP_MEMORY_SCOPE_AGENT);
        int prev = __hip_atomic_fetch_add(counter, 1, __ATOMIC_ACQ_REL,
                                          __HIP_MEMORY_SCOPE_AGENT);
        s_last = (prev == NBLK - 1) ? 1 : 0;
    }
    __syncthreads();
    if (s_last) {
        if (tid < NBLK)
            red[tid] = __hip_atomic_load(&partial[tid], __ATOMIC_RELAXED,
                                         __HIP_MEMORY_SCOPE_AGENT);
        __syncthreads();
        if (tid == 0) {
            float sum = 0.0f;
            int nvalid = 0;
            for (int s = 0; s < NSLICE; ++s) {
                int ng = gcnt[s];
                int np_ = pcnt[s];
                if (ng > 0 && np_ > 0) {
                    float gs = 0.0f, ps = 0.0f;
                    for (int k = 0; k < NSPLIT; ++k) {
                        gs += red[(s * 2 + 0) * NSPLIT + k];
                        ps += red[(s * 2 + 1) * NSPLIT + k];
                    }
                    float ahd = 0.5f * (gs / (float)ng + ps / (float)np_);
                    sum += 1.0f - 1.0f / (1.0f + ahd);
                    nvalid++;
                }
            }
            out[0] = nvalid ? (sum / (float)nvalid) : NAN;
        }
    }
}

// ---------------------------------------------------------------------------
// Workspace layout (bytes):
//   [0,       256K)    bm     : 2 x 16 x 256 x 4 u64  (mask bitmaps)
//   [262144,  512K)    ebm    : 2 x 16 x 256 x 4 u64  (truncated edge bitmaps)
//   [524288,  1M)      gpts   : 16 x 4096 float2
//   [1048576, 1.5M)    ppts   : 16 x 4096 float2
//   [1572864, +64)     gcnt   : 16 int
//   [1572928, +64)     pcnt   : 16 int
//   [1572992, +1K)     partial: 256 float
//   [1574016, +4)      counter: 1 int
// ---------------------------------------------------------------------------
extern "C" void kernel_launch(void* const* d_in, const int* in_sizes, int n_in,
                              void* d_out, int out_size, void* d_ws, size_t ws_size,
                              hipStream_t stream) {
    const float* gth = (const float*)d_in[0];
    const float* pred = (const float*)d_in[1];
    float* out = (float*)d_out;
    char* ws = (char*)d_ws;

    u64* bm = (u64*)(ws);
    u64* ebm = (u64*)(ws + 262144);
    float2* gpts = (float2*)(ws + 524288);
    float2* ppts = (float2*)(ws + 1048576);
    int* gcnt = (int*)(ws + 1572864);
    int* pcnt = (int*)(ws + 1572928);
    float* partial = (float*)(ws + 1572992);
    int* counter = (int*)(ws + 1574016);

    k1_binpack<<<8192, 256, 0, stream>>>(gth, pred, bm, counter);
    k2_edge_compact<<<32, 256, 0, stream>>>(bm, gpts, ppts, ebm, gcnt, pcnt);
    k3_sd_nn<<<NBLK, 1024, 147456, stream>>>(gpts, ppts, gcnt, pcnt, ebm,
                                             partial, counter, out);
}